// Round 7
// baseline (211.054 us; speedup 1.0000x reference)
//
#include <hip/hip_runtime.h>
#include <hip/hip_bf16.h>

typedef float v2f __attribute__((ext_vector_type(2)));

// ---------------- problem constants ----------------
#define B_    4
#define C_    4
#define Q_    8
#define J_    5
#define T_    15
#define NSIG  65536
#define N2SIG 32768
#define NOUT  16384
#define NCH   (B_ * C_)

// ---------------- wavelet filters ----------------
constexpr float H0Oc[13] = {
    -0.00455690456024f, -0.00543947593727f,  0.01702522388155f,  0.02382538479492f,
    -0.10671180468666f,  0.01186609203379f,  0.56881042071212f,  0.75614564389252f,
     0.27529538466888f, -0.11720388769911f, -0.03887280126882f,  0.03466034684485f,
    -0.00388321199915f };
constexpr float H1Oc[13] = {
    -0.00388321199915f, -0.03466034684485f, -0.03887280126882f,  0.11720388769911f,
     0.27529538466888f, -0.75614564389252f,  0.56881042071212f, -0.01186609203379f,
    -0.10671180468666f, -0.02382538479492f,  0.01702522388155f,  0.00543947593727f,
    -0.00455690456024f };
constexpr float H0Ac[10] = {
     0.03516384f, 0.0f, -0.08832942f, 0.23389032f, 0.76027237f,
     0.58751830f, 0.0f, -0.11430184f, 0.0f, 0.0f };
constexpr float H0Bc[10] = {
     0.0f, 0.0f, -0.11430184f, 0.0f, 0.58751830f,
     0.76027237f, 0.23389032f, -0.08832942f, 0.0f, 0.03516384f };
constexpr float H1Ac[10] = {
     0.0f, 0.0f, -0.11430184f, 0.0f, 0.58751830f,
    -0.76027237f, 0.23389032f, 0.08832942f, 0.0f, -0.03516384f };
constexpr float H1Bc[10] = {
    -0.03516384f, 0.0f, 0.08832942f, 0.23389032f, -0.76027237f,
     0.58751830f, 0.0f, -0.11430184f, 0.0f, 0.0f };

// fused two-stage lowpass+decimate: out[m] = sum_n g[n] * u[4m + n - 18]
struct Gtab { float v[37]; };
constexpr Gtab make_g() {
    Gtab g{};
    for (int n = 0; n < 37; ++n) {
        float s = 0.f;
        for (int k = 0; k < 13; ++k) {
            int l = n - 2 * k;
            if (l >= 0 && l < 13) s += H0Oc[k] * H0Oc[l];
        }
        g.v[n] = s;
    }
    return g;
}
constexpr Gtab cG = make_g();

// ---------------- tiling ----------------
#define M2    256                // final outputs per tile
#define NUcnt 1057               // 4*(M2-1) + 37
#define NUP   1064               // U plane stride (uint2 elems)
#define NBcnt 1169               // bp pairs needed
#define NBP   1200               // sRI alloc (v2f)
#define S_    1320               // x window (halo 73 left / 74 right)

// LDS carve (floats): X [0,1320) | L1 [1320,2640) | PP0=v2f@0 | PP1=v2f@2640 |
// UA=uint2@0 (1064 -> floats [0,2128)) | UB=uint2@2128 | sRI=v2f@5280 (1200)
#define SMEM_FLOATS (5280 + 2 * NBP)   // 7680 floats = 30720 B

__device__ __forceinline__ v2f zmask(v2f a, bool ok) {
    if (!ok) { a.x = 0.f; a.y = 0.f; }
    return a;
}
// round-half-up bf16 pack: low half = a, high half = b
__device__ __forceinline__ unsigned pack2bf(float a, float b) {
    unsigned ua = __float_as_uint(a) + 0x8000u;
    unsigned ub = __float_as_uint(b) + 0x8000u;
    return (ua >> 16) | (ub & 0xffff0000u);
}
__device__ __forceinline__ float unpk_lo(unsigned x) { return __uint_as_float(x << 16); }
__device__ __forceinline__ float unpk_hi(unsigned x) { return __uint_as_float(x & 0xffff0000u); }

// ---------------- post stage: single-pass 8q + bf16 U + fused downsample ----
template<int D>
__device__ __forceinline__ void post_stage(
        const v2f* __restrict__ sRI, uint2* __restrict__ UA, uint2* __restrict__ UB,
        const float* __restrict__ cw, const float* __restrict__ roots,
        float beta, int j, int b, int c, int m0, int mt, int tid,
        float* __restrict__ out) {
    const float lg_is = -0.5f * (float)j;                // log2(inv_scale)
    const float beta2 = beta * exp2f(0.5f * (float)j);   // beta * scale
    const int   u_lo  = 4 * m0 - 18;
    const float* wbase = cw + (size_t)(j * 32 + c * 8) * T_;

    float al[8], cq[8];
    #pragma unroll
    for (int q = 0; q < 8; ++q) {
        al[q] = 1.f / (1.f + __expf(-roots[j * 32 + c * 8 + q]));
        cq[q] = al[q] * lg_is;
    }

    // ---- u stage: 15 taps read once, all 8 q's computed, bf16x4 packed ----
    for (int i = tid; i < NUcnt; i += 256) {
        const int n = u_lo + i;
        const bool ok = ((unsigned)n < (unsigned)NSIG);
        const v2f* tp = sRI + (i + 56 - 7 * D);
        v2f tap[T_];
        #pragma unroll
        for (int t = 0; t < T_; t++) tap[t] = tp[t * D];
        float uq[8];
        #pragma unroll
        for (int q = 0; q < 8; ++q) {
            v2f ri; ri.x = 0.f; ri.y = 0.f;
            #pragma unroll
            for (int t = 0; t < T_; t++) ri += wbase[q * T_ + t] * tap[t];
            float z2 = fmaf(ri.x, ri.x, ri.y * ri.y);
            float us = sqrtf(z2);
            float lg = __log2f(us + beta2);
            float u  = exp2f(fmaf(al[q], lg, cq[q]));
            uq[q] = ok ? u : 0.f;
        }
        uint2 pa, pb;
        pa.x = pack2bf(uq[0], uq[1]); pa.y = pack2bf(uq[2], uq[3]);
        pb.x = pack2bf(uq[4], uq[5]); pb.y = pack2bf(uq[6], uq[7]);
        UA[i] = pa; UB[i] = pb;
    }
    __syncthreads();

    // ---- fused 37-tap stride-4 downsample on bf16x4 planes ----
    {
        const int m = m0 + tid;
        const bool edge = (mt == 0 && tid < 3) || (mt == 63 && tid >= 253);
        #pragma unroll
        for (int pl = 0; pl < 2; ++pl) {
            const uint2* up = pl ? UB : UA;
            float a0 = 0.f, a1 = 0.f, a2 = 0.f, a3 = 0.f;
            #pragma unroll
            for (int nn = 0; nn < 37; ++nn) {
                uint2 t = up[4 * tid + nn];
                a0 = fmaf(cG.v[nn], unpk_lo(t.x), a0);
                a1 = fmaf(cG.v[nn], unpk_hi(t.x), a1);
                a2 = fmaf(cG.v[nn], unpk_lo(t.y), a2);
                a3 = fmaf(cG.v[nn], unpk_hi(t.y), a3);
            }
            if (edge) {
                // exact two-stage computation honoring v-plane masking
                float e0 = 0.f, e1 = 0.f, e2 = 0.f, e3 = 0.f;
                for (int k = 0; k < 13; ++k) {
                    int p = 2 * m + k - 6;
                    if (p < 0 || p >= N2SIG) continue;
                    float v0 = 0.f, v1 = 0.f, v2 = 0.f, v3 = 0.f;
                    for (int l = 0; l < 13; ++l) {
                        uint2 t = up[4 * tid + 2 * k + l];
                        v0 = fmaf(H0Oc[l], unpk_lo(t.x), v0);
                        v1 = fmaf(H0Oc[l], unpk_hi(t.x), v1);
                        v2 = fmaf(H0Oc[l], unpk_lo(t.y), v2);
                        v3 = fmaf(H0Oc[l], unpk_hi(t.y), v3);
                    }
                    e0 = fmaf(H0Oc[k], v0, e0); e1 = fmaf(H0Oc[k], v1, e1);
                    e2 = fmaf(H0Oc[k], v2, e2); e3 = fmaf(H0Oc[k], v3, e3);
                }
                a0 = e0; a1 = e1; a2 = e2; a3 = e3;
            }
            const int o = c * Q_ + pl * 4;
            float* ob = out + ((size_t)b * 160 + j * 32 + o) * NOUT + m;
            ob[0]        = a0;
            ob[NOUT]     = a1;
            ob[2 * NOUT] = a2;
            ob[3 * NOUT] = a3;
        }
    }
}

// ---------------- fused kernel ----------------
__global__ __launch_bounds__(256, 3) void murenn_all(
        const float* __restrict__ x,
        const float* __restrict__ cw,
        const float* __restrict__ roots,
        const float* __restrict__ beta_p,
        float* __restrict__ out) {
    __shared__ __align__(16) float smem[SMEM_FLOATS];
    float* X   = smem;
    float* L1  = smem + S_;
    v2f*   PP0 = (v2f*)smem;
    v2f*   PP1 = (v2f*)(smem + 2 * S_);
    uint2* UA  = (uint2*)smem;
    uint2* UB  = (uint2*)(smem + 2 * NUP);
    v2f*   sRI = (v2f*)(smem + 4 * S_);

    const int tid = threadIdx.x;
    const int mt  = blockIdx.x;              // 0..63
    const int ch  = blockIdx.y;              // b*C + c
    const int j   = blockIdx.z;              // 0..4
    const int b   = ch >> 2, c = ch & 3;
    const int m0  = mt * M2;
    const int ofs = 4 * m0 - 147;            // window start (bp index 0 at p=73)
    const float beta = beta_p[0];
    const float* xc = x + (size_t)ch * NSIG;

    // ---- load x window ----
    for (int p = tid; p < S_; p += 256) {
        int g = ofs + p;
        X[p] = ((unsigned)g < (unsigned)NSIG) ? xc[g] : 0.f;
    }
    __syncthreads();

    // ---- UDTCWT chain (R5 form: lane-stride-1, conflict-light) ----
    if (j == 0) {
        for (int i = tid; i < NBcnt; i += 256) {
            int p = 73 + i, g = ofs + p;
            float a = 0.f;
            #pragma unroll
            for (int k = 0; k < 13; k++) a += H1Oc[k] * X[p + k - 6];
            if ((unsigned)g >= (unsigned)NSIG) a = 0.f;
            v2f r; r.x = a; r.y = a;
            sRI[i] = r;
        }
    } else {
        // lv0: la1 = conv13(x, H0O) -> L1
        for (int p = 6 + tid; p < 1313; p += 256) {
            int g = ofs + p;
            float a = 0.f;
            #pragma unroll
            for (int k = 0; k < 13; k++) a += H0Oc[k] * X[p + k - 6];
            L1[p] = ((unsigned)g < (unsigned)NSIG) ? a : 0.f;
        }
        __syncthreads();
        if (j == 1) {
            for (int i = tid; i < NBcnt; i += 256) {
                int p = 73 + i, g = ofs + p;
                v2f r; r.x = 0.f; r.y = 0.f;
                #pragma unroll
                for (int k = 0; k < 10; k++) {
                    v2f hk; hk.x = H1Ac[k]; hk.y = H1Bc[k];
                    r += hk * L1[p + k - 4];
                }
                sRI[i] = zmask(r, (unsigned)g < (unsigned)NSIG);
            }
        } else {
            // lv1 (d=1, pad 4): (la2,lb2) -> PP1
            for (int p = 10 + tid; p < 1308; p += 256) {
                int g = ofs + p;
                v2f a; a.x = 0.f; a.y = 0.f;
                #pragma unroll
                for (int k = 0; k < 10; k++) {
                    v2f hk; hk.x = H0Ac[k]; hk.y = H0Bc[k];
                    a += hk * L1[p + k - 4];
                }
                PP1[p] = zmask(a, (unsigned)g < (unsigned)NSIG);
            }
            __syncthreads();
            if (j == 2) {
                for (int i = tid; i < NBcnt; i += 256) {
                    int p = 73 + i, g = ofs + p;
                    v2f r; r.x = 0.f; r.y = 0.f;
                    #pragma unroll
                    for (int k = 0; k < 10; k++) {
                        v2f hk; hk.x = H1Ac[k]; hk.y = H1Bc[k];
                        r += hk * PP1[p + 2 * k - 9];
                    }
                    sRI[i] = zmask(r, (unsigned)g < (unsigned)NSIG);
                }
            } else {
                // lv2 (d=2, pad 9): (la3,lb3) -> PP0  (X/L1 dead)
                for (int p = 19 + tid; p < 1299; p += 256) {
                    int g = ofs + p;
                    v2f a; a.x = 0.f; a.y = 0.f;
                    #pragma unroll
                    for (int k = 0; k < 10; k++) {
                        v2f hk; hk.x = H0Ac[k]; hk.y = H0Bc[k];
                        a += hk * PP1[p + 2 * k - 9];
                    }
                    PP0[p] = zmask(a, (unsigned)g < (unsigned)NSIG);
                }
                __syncthreads();
                if (j == 3) {
                    for (int i = tid; i < NBcnt; i += 256) {
                        int p = 73 + i, g = ofs + p;
                        v2f r; r.x = 0.f; r.y = 0.f;
                        #pragma unroll
                        for (int k = 0; k < 10; k++) {
                            v2f hk; hk.x = H1Ac[k]; hk.y = H1Bc[k];
                            r += hk * PP0[p + 4 * k - 18];
                        }
                        sRI[i] = zmask(r, (unsigned)g < (unsigned)NSIG);
                    }
                } else {
                    // lv3 (d=4, pad 18): (la4,lb4) -> PP1 (old PP1 dead)
                    for (int p = 37 + tid; p < 1281; p += 256) {
                        int g = ofs + p;
                        v2f a; a.x = 0.f; a.y = 0.f;
                        #pragma unroll
                        for (int k = 0; k < 10; k++) {
                            v2f hk; hk.x = H0Ac[k]; hk.y = H0Bc[k];
                            a += hk * PP0[p + 4 * k - 18];
                        }
                        PP1[p] = zmask(a, (unsigned)g < (unsigned)NSIG);
                    }
                    __syncthreads();
                    // j == 4 bandpass (d=8, pad 36)
                    for (int i = tid; i < NBcnt; i += 256) {
                        int p = 73 + i, g = ofs + p;
                        v2f r; r.x = 0.f; r.y = 0.f;
                        #pragma unroll
                        for (int k = 0; k < 10; k++) {
                            v2f hk; hk.x = H1Ac[k]; hk.y = H1Bc[k];
                            r += hk * PP1[p + 8 * k - 36];
                        }
                        sRI[i] = zmask(r, (unsigned)g < (unsigned)NSIG);
                    }
                }
            }
        }
    }
    __syncthreads();
    // PP/X/L1 dead: region becomes U planes.

    if (j == 0)      post_stage<1>(sRI, UA, UB, cw, roots, beta, 0, b, c, m0, mt, tid, out);
    else if (j == 1) post_stage<1>(sRI, UA, UB, cw, roots, beta, 1, b, c, m0, mt, tid, out);
    else if (j == 2) post_stage<2>(sRI, UA, UB, cw, roots, beta, 2, b, c, m0, mt, tid, out);
    else if (j == 3) post_stage<4>(sRI, UA, UB, cw, roots, beta, 3, b, c, m0, mt, tid, out);
    else             post_stage<8>(sRI, UA, UB, cw, roots, beta, 4, b, c, m0, mt, tid, out);
}

// ---------------- launch ----------------
extern "C" void kernel_launch(void* const* d_in, const int* in_sizes, int n_in,
                              void* d_out, int out_size, void* d_ws, size_t ws_size,
                              hipStream_t stream) {
    (void)in_sizes; (void)n_in; (void)out_size; (void)d_ws; (void)ws_size;
    const float* x     = (const float*)d_in[0];
    const float* cw    = (const float*)d_in[1];
    const float* roots = (const float*)d_in[2];
    const float* beta  = (const float*)d_in[3];
    float* out = (float*)d_out;

    dim3 grid(NOUT / M2, NCH, J_);       // (64, 16, 5)
    murenn_all<<<grid, 256, 0, stream>>>(x, cw, roots, beta, out);
}